// Round 1
// baseline (529.191 us; speedup 1.0000x reference)
//
#include <hip/hip_runtime.h>
#include <hip/hip_bf16.h>

#define NB 62
#define NC 5
#define KTOP 49

__device__ __forceinline__ float sigmf(float x) {
    return 1.0f / (1.0f + __expf(-x));
}

__launch_bounds__(64)
__global__ void encoder_kernel(
    const float* __restrict__ g_x,
    const float* __restrict__ c0w, const float* __restrict__ c0b,
    const float* __restrict__ m0,  const float* __restrict__ f0w,
    const float* __restrict__ f0b, const float* __restrict__ g0w,
    const float* __restrict__ g0b,
    const float* __restrict__ c1w, const float* __restrict__ c1b,
    const float* __restrict__ m1,  const float* __restrict__ f1w,
    const float* __restrict__ f1b, const float* __restrict__ g1w,
    const float* __restrict__ g1b,
    const float* __restrict__ caw1, const float* __restrict__ caw2,
    const float* __restrict__ saw,  const float* __restrict__ sab,
    const float* __restrict__ fc1w, const float* __restrict__ fc1b,
    const float* __restrict__ fc2w, const float* __restrict__ fc2b,
    float* __restrict__ g_out)
{
    const int b   = blockIdx.x;
    const int tid = threadIdx.x;

    __shared__ float s_xt[3][NB][NC];   // feature maps transposed: [layer][n][c]
    __shared__ float s_xc[NB][8];       // conv output transposed [n][c], stride 8 for float4
    __shared__ float s_mem[NB][8];      // mem transposed [m][c]
    __shared__ float s_adj[NB * 64];    // adjacency, xor-swizzled [n][m ^ (n&31)]
    __shared__ float s_g[3 * NC * NB];  // 930 post-CBAM features, flat c*62+n
    __shared__ float s_mx[16], s_av[16], s_ca[16];
    __shared__ float s_smax[64], s_smean[64];
    __shared__ float s_h1[64];

    // ---- load input x[b] -> s_xt[0][n][c]  (flat idx = c*62+n, coalesced) ----
    for (int i = tid; i < NC * NB; i += 64) {
        const int c = i / NB, n = i - c * NB;
        s_xt[0][n][c] = g_x[(size_t)b * (NC * NB) + i];
    }
    __syncthreads();

    const float scale = 0.44721359549995793f; // 1/sqrt(5)

    for (int l = 0; l < 2; ++l) {
        const float* conv_w = l ? c1w : c0w;
        const float* conv_b = l ? c1b : c0b;
        const float* memp   = l ? m1  : m0;
        const float* gfc_w  = l ? f1w : f0w;
        const float* gfc_b  = l ? f1b : f0b;
        const float* gcn_w  = l ? g1w : g0w;
        const float* gcn_b  = l ? g1b : g0b;

        // stage mem transposed: s_mem[m][c] = mem[c*62+m]
        for (int i = tid; i < NC * NB; i += 64) {
            const int c = i / NB, m = i - c * NB;
            s_mem[m][c] = memp[i];
        }

        // small uniform params -> (hopefully) SGPRs
        float cw[25], cb[5], gw[25], gb[5];
        #pragma unroll
        for (int i = 0; i < 25; ++i) cw[i] = conv_w[i];
        #pragma unroll
        for (int i = 0; i < 5; ++i)  cb[i] = conv_b[i];
        #pragma unroll
        for (int i = 0; i < 25; ++i) gw[i] = gcn_w[i];
        #pragma unroll
        for (int i = 0; i < 5; ++i)  gb[i] = gcn_b[i];
        const float w0 = gfc_w[0], w1 = gfc_w[1], b0 = gfc_b[0];

        // ---- conv1x1: thread n computes its column of xc ----
        float xo0 = 0, xo1 = 0, xo2 = 0, xo3 = 0, xo4 = 0;
        if (tid < NB) {
            const int n = tid;
            float xn[5];
            #pragma unroll
            for (int c = 0; c < 5; ++c) xn[c] = s_xt[l][n][c];
            xo0 = cb[0]; xo1 = cb[1]; xo2 = cb[2]; xo3 = cb[3]; xo4 = cb[4];
            #pragma unroll
            for (int c = 0; c < 5; ++c) {
                xo0 += cw[0 * 5 + c] * xn[c];
                xo1 += cw[1 * 5 + c] * xn[c];
                xo2 += cw[2 * 5 + c] * xn[c];
                xo3 += cw[3 * 5 + c] * xn[c];
                xo4 += cw[4 * 5 + c] * xn[c];
            }
            s_xc[n][0] = xo0; s_xc[n][1] = xo1; s_xc[n][2] = xo2;
            s_xc[n][3] = xo3; s_xc[n][4] = xo4;
        }
        __syncthreads();

        // ---- row phase: thread n owns row n of s1/s2/af fully in registers ----
        if (tid < NB) {
            const int n = tid;
            float r1[NB];
            float r2[64];
            #pragma unroll
            for (int m = 0; m < NB; ++m) {
                const float4 me = *(const float4*)&s_mem[m][0];
                const float  me4 = s_mem[m][4];
                const float4 xm = *(const float4*)&s_xc[m][0];
                const float  xm4 = s_xc[m][4];
                float s1 = xo0 * me.x + xo1 * me.y + xo2 * me.z + xo3 * me.w + xo4 * me4;
                float s2 = xo0 * xm.x + xo1 * xm.y + xo2 * xm.z + xo3 * xm.w + xo4 * xm4;
                r1[m] = fmaxf(s1 * scale, 0.0f);
                r2[m] = fmaxf(s2 * scale, 0.0f);
            }
            // softmax(r1)  (normalization deferred into the combine)
            float mx1 = r1[0];
            #pragma unroll
            for (int m = 1; m < NB; ++m) mx1 = fmaxf(mx1, r1[m]);
            float sum1 = 0.0f;
            #pragma unroll
            for (int m = 0; m < NB; ++m) { r1[m] = __expf(r1[m] - mx1); sum1 += r1[m]; }
            const float inv1 = 1.0f / sum1;
            // softmax(r2)
            float mx2 = r2[0];
            #pragma unroll
            for (int m = 1; m < NB; ++m) mx2 = fmaxf(mx2, r2[m]);
            float sum2 = 0.0f;
            #pragma unroll
            for (int m = 0; m < NB; ++m) { r2[m] = __expf(r2[m] - mx2); sum2 += r2[m]; }
            const float inv2 = 1.0f / sum2;
            // af = w0*a1 + w1*a2 + b0
            #pragma unroll
            for (int m = 0; m < NB; ++m)
                r1[m] = b0 + (r1[m] * inv1) * w0 + (r2[m] * inv2) * w1;
            // softmax(af), normalized in place (ranking must see normalized values)
            float mxa = r1[0];
            #pragma unroll
            for (int m = 1; m < NB; ++m) mxa = fmaxf(mxa, r1[m]);
            float suma = 0.0f;
            #pragma unroll
            for (int m = 0; m < NB; ++m) { r1[m] = __expf(r1[m] - mxa); suma += r1[m]; }
            const float inva = 1.0f / suma;
            #pragma unroll
            for (int m = 0; m < NB; ++m) r1[m] *= inva;

            // ---- find 49th-largest value: bitonic-sort a copy (values only) ----
            #pragma unroll
            for (int m = 0; m < NB; ++m) r2[m] = r1[m];
            r2[62] = INFINITY; r2[63] = INFINITY;
            #pragma unroll
            for (int k = 2; k <= 64; k <<= 1) {
                #pragma unroll
                for (int j = k >> 1; j > 0; j >>= 1) {
                    #pragma unroll
                    for (int i = 0; i < 64; ++i) {
                        const int p = i ^ j;
                        if (p > i) {
                            const bool up = ((i & k) == 0);
                            const float a = r2[i], c = r2[p];
                            r2[i] = up ? fminf(a, c) : fmaxf(a, c);
                            r2[p] = up ? fmaxf(a, c) : fminf(a, c);
                        }
                    }
                }
            }
            const float vth = r2[13]; // 14th smallest == 49th largest (ascending sort)

            // ---- tie-aware selection identical to jax.lax.top_k (lower index first) ----
            int G = 0;
            #pragma unroll
            for (int m = 0; m < NB; ++m) G += (r1[m] > vth) ? 1 : 0;
            int eq = 0;
            #pragma unroll
            for (int m = 0; m < NB; ++m) {
                const bool e  = (r1[m] == vth);
                const bool ss = (r1[m] > vth) || (e && (G + eq) < KTOP);
                s_adj[n * 64 + (m ^ (n & 31))] = ss ? r1[m] : 0.0f;
                eq += e ? 1 : 0;
            }
        }
        __syncthreads();

        // ---- diffusion + gcn mix + skip: thread m computes output column m ----
        if (tid < NB) {
            const int m = tid;
            float y0 = 0, y1 = 0, y2 = 0, y3 = 0, y4 = 0;
            for (int n = 0; n < NB; ++n) {
                const float a = s_adj[n * 64 + (m ^ (n & 31))];
                const float4 xv = *(const float4*)&s_xc[n][0];
                const float  xv4 = s_xc[n][4];
                y0 += xv.x * a; y1 += xv.y * a; y2 += xv.z * a;
                y3 += xv.w * a; y4 += xv4 * a;
            }
            #pragma unroll
            for (int o = 0; o < 5; ++o) {
                const float z = gb[o] + gw[o * 5 + 0] * y0 + gw[o * 5 + 1] * y1 +
                                gw[o * 5 + 2] * y2 + gw[o * 5 + 3] * y3 + gw[o * 5 + 4] * y4;
                s_xt[l + 1][m][o] = z + s_xt[l][m][o];
            }
        }
        __syncthreads();
    }

    // ================= CBAM =================
    // channel max / mean
    if (tid < 15) {
        const int lidx = tid / 5, cc = tid - lidx * 5;
        float mxv = -INFINITY, sm = 0.0f;
        for (int n = 0; n < NB; ++n) {
            const float v = s_xt[lidx][n][cc];
            mxv = fmaxf(mxv, v);
            sm += v;
        }
        s_mx[tid] = mxv;
        s_av[tid] = sm * (1.0f / 62.0f);
    }
    __syncthreads();
    // channel attention (SE MLP, no bias)
    if (tid < 15) {
        float t = 0.0f;
        #pragma unroll
        for (int o = 0; o < 3; ++o) {
            float am = 0.0f, aa = 0.0f;
            #pragma unroll
            for (int c = 0; c < 15; ++c) {
                const float w = caw1[o * 15 + c];
                am += s_mx[c] * w;
                aa += s_av[c] * w;
            }
            t += (fmaxf(am, 0.0f) + fmaxf(aa, 0.0f)) * caw2[tid * 3 + o];
        }
        s_ca[tid] = sigmf(t);
    }
    __syncthreads();
    // spatial descriptors over CA-scaled maps
    float og[15];
    if (tid < NB) {
        const int n = tid;
        float smx = -INFINITY, ssum = 0.0f;
        #pragma unroll
        for (int c = 0; c < 15; ++c) {
            const int lidx = c / 5, cc = c - lidx * 5;
            const float v = s_xt[lidx][n][cc] * s_ca[c];
            og[c] = v;
            smx = fmaxf(smx, v);
            ssum += v;
        }
        s_smax[n]  = smx;
        s_smean[n] = ssum * (1.0f / 15.0f);
    }
    __syncthreads();
    // 3x1 spatial conv (only kw=1 column of the 3x3 survives W=1 padding) + residual
    if (tid < NB) {
        const int n = tid;
        float t = sab[0];
        #pragma unroll
        for (int kh = 0; kh < 3; ++kh) {
            const int nn = n - 1 + kh;
            const int ncl = nn < 0 ? 0 : (nn > NB - 1 ? NB - 1 : nn);
            const float msk = (nn >= 0 && nn < NB) ? 1.0f : 0.0f;
            t += msk * (s_smax[ncl] * saw[kh * 3 + 1] + s_smean[ncl] * saw[9 + kh * 3 + 1]);
        }
        const float sa = sigmf(t);
        #pragma unroll
        for (int c = 0; c < 15; ++c) {
            const int lidx = c / 5, cc = c - lidx * 5;
            s_g[c * NB + n] = og[c] * sa + s_xt[lidx][n][cc];
        }
    }
    __syncthreads();

    // ================= FC head =================
    {
        float acc = fc1b[tid];
        const float* wr = fc1w + (size_t)tid * 930;
        #pragma unroll 4
        for (int i = 0; i < 928; i += 2) {
            const float2 wv = *(const float2*)(wr + i);
            const float2 gv = *(const float2*)(&s_g[i]);
            acc += wv.x * gv.x + wv.y * gv.y;
        }
        acc += wr[928] * s_g[928] + wr[929] * s_g[929];
        s_h1[tid] = fmaxf(acc, 0.0f);
    }
    __syncthreads();
    {
        float acc = fc2b[tid];
        const float* wr = fc2w + tid * 64;
        #pragma unroll
        for (int k = 0; k < 64; k += 4) {
            const float4 wv = *(const float4*)(wr + k);
            acc += wv.x * s_h1[k] + wv.y * s_h1[k + 1] + wv.z * s_h1[k + 2] + wv.w * s_h1[k + 3];
        }
        g_out[(size_t)b * 64 + tid] = fmaxf(acc, 0.0f);
    }
}

extern "C" void kernel_launch(void* const* d_in, const int* in_sizes, int n_in,
                              void* d_out, int out_size, void* d_ws, size_t ws_size,
                              hipStream_t stream) {
    const float* X    = (const float*)d_in[0];
    const float* C0W  = (const float*)d_in[1];
    const float* C0B  = (const float*)d_in[2];
    const float* M0   = (const float*)d_in[3];
    const float* F0W  = (const float*)d_in[4];
    const float* F0B  = (const float*)d_in[5];
    const float* G0W  = (const float*)d_in[6];
    const float* G0B  = (const float*)d_in[7];
    const float* C1W  = (const float*)d_in[8];
    const float* C1B  = (const float*)d_in[9];
    const float* M1   = (const float*)d_in[10];
    const float* F1W  = (const float*)d_in[11];
    const float* F1B  = (const float*)d_in[12];
    const float* G1W  = (const float*)d_in[13];
    const float* G1B  = (const float*)d_in[14];
    const float* CAW1 = (const float*)d_in[15];
    const float* CAW2 = (const float*)d_in[16];
    const float* SAW  = (const float*)d_in[17];
    const float* SAB  = (const float*)d_in[18];
    const float* FC1W = (const float*)d_in[19];
    const float* FC1B = (const float*)d_in[20];
    const float* FC2W = (const float*)d_in[21];
    const float* FC2B = (const float*)d_in[22];

    const int B = in_sizes[0] / (NC * NB);

    encoder_kernel<<<B, 64, 0, stream>>>(
        X, C0W, C0B, M0, F0W, F0B, G0W, G0B,
        C1W, C1B, M1, F1W, F1B, G1W, G1B,
        CAW1, CAW2, SAW, SAB, FC1W, FC1B, FC2W, FC2B,
        (float*)d_out);
}

// Round 2
// 333.690 us; speedup vs baseline: 1.5859x; 1.5859x over previous
//
#include <hip/hip_runtime.h>
#include <hip/hip_bf16.h>

#define NB 62
#define NC 5
#define KTOP 49

__device__ __forceinline__ float sigmf(float x) {
    return 1.0f / (1.0f + __expf(-x));
}

__launch_bounds__(64, 2)
__global__ void encoder_kernel(
    const float* __restrict__ g_x,
    const float* __restrict__ c0w, const float* __restrict__ c0b,
    const float* __restrict__ m0,  const float* __restrict__ f0w,
    const float* __restrict__ f0b, const float* __restrict__ g0w,
    const float* __restrict__ g0b,
    const float* __restrict__ c1w, const float* __restrict__ c1b,
    const float* __restrict__ m1,  const float* __restrict__ f1w,
    const float* __restrict__ f1b, const float* __restrict__ g1w,
    const float* __restrict__ g1b,
    const float* __restrict__ caw1, const float* __restrict__ caw2,
    const float* __restrict__ saw,  const float* __restrict__ sab,
    const float* __restrict__ fc1w, const float* __restrict__ fc1b,
    const float* __restrict__ fc2w, const float* __restrict__ fc2b,
    float* __restrict__ g_out)
{
    const int b   = blockIdx.x;
    const int tid = threadIdx.x;

    // LDS budget (goal: 7 blocks/CU):
    //   s_adj  62*63*4 = 15624  (adjacency, pad-1 stride => conflict-free rows AND cols)
    //   s_xt   3*62*5*4 = 3720  (feature maps per layer, [n][c])
    //   s_xm   62*10*4  = 2480  (xc[0..3] | mem[0..3] | xc4 | mem4, float4-aligned)
    //   small  960
    // total 22784 B
    __shared__ __align__(16) float s_adj[NB * 63];
    __shared__ float s_xt[3][NB][NC];
    __shared__ __align__(16) float s_xm[NB][10];
    __shared__ float s_mx[16], s_av[16], s_ca[16];
    __shared__ float s_smax[64], s_smean[64];
    __shared__ float s_h1[64];

    float* s_g = s_adj;  // alias: s_g (930 floats) used only after adjacency is dead

    // ---- load input x[b] -> s_xt[0][n][c]  (flat idx = c*62+n, coalesced) ----
    for (int i = tid; i < NC * NB; i += 64) {
        const int c = i / NB, n = i - c * NB;
        s_xt[0][n][c] = g_x[(size_t)b * (NC * NB) + i];
    }
    __syncthreads();

    const float scale = 0.44721359549995793f; // 1/sqrt(5)

    for (int l = 0; l < 2; ++l) {
        const float* conv_w = l ? c1w : c0w;
        const float* conv_b = l ? c1b : c0b;
        const float* memp   = l ? m1  : m0;
        const float* gfc_w  = l ? f1w : f0w;
        const float* gfc_b  = l ? f1b : f0b;
        const float* gcn_w  = l ? g1w : g0w;
        const float* gcn_b  = l ? g1b : g0b;

        // stage mem: s_xm[m][4+c] (c<4), s_xm[m][9] (c==4)
        for (int i = tid; i < NC * NB; i += 64) {
            const int c = i / NB, m = i - c * NB;
            s_xm[m][c < 4 ? 4 + c : 9] = memp[i];
        }

        float cw[25], cb[5], gw[25], gb[5];
        #pragma unroll
        for (int i = 0; i < 25; ++i) cw[i] = conv_w[i];
        #pragma unroll
        for (int i = 0; i < 5; ++i)  cb[i] = conv_b[i];
        #pragma unroll
        for (int i = 0; i < 25; ++i) gw[i] = gcn_w[i];
        #pragma unroll
        for (int i = 0; i < 5; ++i)  gb[i] = gcn_b[i];
        const float w0 = gfc_w[0], w1 = gfc_w[1], b0 = gfc_b[0];

        // ---- conv1x1: thread n computes its column of xc ----
        float xo0 = 0, xo1 = 0, xo2 = 0, xo3 = 0, xo4 = 0;
        if (tid < NB) {
            const int n = tid;
            float xn[5];
            #pragma unroll
            for (int c = 0; c < 5; ++c) xn[c] = s_xt[l][n][c];
            xo0 = cb[0]; xo1 = cb[1]; xo2 = cb[2]; xo3 = cb[3]; xo4 = cb[4];
            #pragma unroll
            for (int c = 0; c < 5; ++c) {
                xo0 = fmaf(cw[0 * 5 + c], xn[c], xo0);
                xo1 = fmaf(cw[1 * 5 + c], xn[c], xo1);
                xo2 = fmaf(cw[2 * 5 + c], xn[c], xo2);
                xo3 = fmaf(cw[3 * 5 + c], xn[c], xo3);
                xo4 = fmaf(cw[4 * 5 + c], xn[c], xo4);
            }
            s_xm[n][0] = xo0; s_xm[n][1] = xo1; s_xm[n][2] = xo2;
            s_xm[n][3] = xo3; s_xm[n][8] = xo4;
        }
        __syncthreads();

        // ---- row phase: thread n owns row n fully in registers (no spills:
        //      r1[62]+r2[64]+~30 live ~ 190 VGPRs, launch_bounds allows 256) ----
        if (tid < NB) {
            float r1[NB];
            float r2[64];
            #pragma unroll
            for (int m = 0; m < NB; ++m) {
                const float4 xc03 = *(const float4*)&s_xm[m][0];
                const float4 me03 = *(const float4*)&s_xm[m][4];
                const float2 t45  = *(const float2*)&s_xm[m][8];
                float s1 = xo0 * me03.x + xo1 * me03.y + xo2 * me03.z + xo3 * me03.w + xo4 * t45.y;
                float s2 = xo0 * xc03.x + xo1 * xc03.y + xo2 * xc03.z + xo3 * xc03.w + xo4 * t45.x;
                r1[m] = fmaxf(s1 * scale, 0.0f);
                r2[m] = fmaxf(s2 * scale, 0.0f);
            }
            // softmax(r1) (normalization folded into combine)
            float mx1 = r1[0];
            #pragma unroll
            for (int m = 1; m < NB; ++m) mx1 = fmaxf(mx1, r1[m]);
            float sum1 = 0.0f;
            #pragma unroll
            for (int m = 0; m < NB; ++m) { r1[m] = __expf(r1[m] - mx1); sum1 += r1[m]; }
            const float inv1 = 1.0f / sum1;
            float mx2 = r2[0];
            #pragma unroll
            for (int m = 1; m < NB; ++m) mx2 = fmaxf(mx2, r2[m]);
            float sum2 = 0.0f;
            #pragma unroll
            for (int m = 0; m < NB; ++m) { r2[m] = __expf(r2[m] - mx2); sum2 += r2[m]; }
            const float inv2 = 1.0f / sum2;
            // af = w0*a1 + w1*a2 + b0
            #pragma unroll
            for (int m = 0; m < NB; ++m)
                r1[m] = b0 + (r1[m] * inv1) * w0 + (r2[m] * inv2) * w1;
            // softmax(af), normalized in place (ranking must see normalized values)
            float mxa = r1[0];
            #pragma unroll
            for (int m = 1; m < NB; ++m) mxa = fmaxf(mxa, r1[m]);
            float suma = 0.0f;
            #pragma unroll
            for (int m = 0; m < NB; ++m) { r1[m] = __expf(r1[m] - mxa); suma += r1[m]; }
            const float inva = 1.0f / suma;
            #pragma unroll
            for (int m = 0; m < NB; ++m) r1[m] *= inva;

            // ---- 49th-largest via value-only bitonic sort of a copy ----
            #pragma unroll
            for (int m = 0; m < NB; ++m) r2[m] = r1[m];
            r2[62] = INFINITY; r2[63] = INFINITY;
            #pragma unroll
            for (int k = 2; k <= 64; k <<= 1) {
                #pragma unroll
                for (int j = k >> 1; j > 0; j >>= 1) {
                    #pragma unroll
                    for (int i = 0; i < 64; ++i) {
                        const int p = i ^ j;
                        if (p > i) {
                            const bool up = ((i & k) == 0);
                            const float a = r2[i], c = r2[p];
                            r2[i] = up ? fminf(a, c) : fmaxf(a, c);
                            r2[p] = up ? fmaxf(a, c) : fminf(a, c);
                        }
                    }
                }
            }
            const float vth = r2[13]; // 14th smallest == 49th largest

            // ---- tie-aware selection == jax.lax.top_k (lower index first) ----
            int G = 0;
            #pragma unroll
            for (int m = 0; m < NB; ++m) G += (r1[m] > vth) ? 1 : 0;
            int eq = 0;
            const int n = tid;
            #pragma unroll
            for (int m = 0; m < NB; ++m) {
                const bool e  = (r1[m] == vth);
                const bool ss = (r1[m] > vth) || (e && (G + eq) < KTOP);
                s_adj[n * 63 + m] = ss ? r1[m] : 0.0f;
                eq += e ? 1 : 0;
            }
        }
        __syncthreads();

        // ---- diffusion + gcn mix + skip: thread m computes output column m ----
        if (tid < NB) {
            const int m = tid;
            float y0 = 0, y1 = 0, y2 = 0, y3 = 0, y4 = 0;
            for (int n = 0; n < NB; ++n) {
                const float a = s_adj[n * 63 + m];
                const float4 xv = *(const float4*)&s_xm[n][0];
                const float  xv4 = s_xm[n][8];
                y0 = fmaf(xv.x, a, y0); y1 = fmaf(xv.y, a, y1); y2 = fmaf(xv.z, a, y2);
                y3 = fmaf(xv.w, a, y3); y4 = fmaf(xv4, a, y4);
            }
            #pragma unroll
            for (int o = 0; o < 5; ++o) {
                const float z = gb[o] + gw[o * 5 + 0] * y0 + gw[o * 5 + 1] * y1 +
                                gw[o * 5 + 2] * y2 + gw[o * 5 + 3] * y3 + gw[o * 5 + 4] * y4;
                s_xt[l + 1][m][o] = z + s_xt[l][m][o];
            }
        }
        __syncthreads();
    }

    // ================= CBAM =================
    if (tid < 15) {
        const int lidx = tid / 5, cc = tid - lidx * 5;
        float mxv = -INFINITY, sm = 0.0f;
        for (int n = 0; n < NB; ++n) {
            const float v = s_xt[lidx][n][cc];
            mxv = fmaxf(mxv, v);
            sm += v;
        }
        s_mx[tid] = mxv;
        s_av[tid] = sm * (1.0f / 62.0f);
    }
    __syncthreads();
    if (tid < 15) {
        float t = 0.0f;
        #pragma unroll
        for (int o = 0; o < 3; ++o) {
            float am = 0.0f, aa = 0.0f;
            #pragma unroll
            for (int c = 0; c < 15; ++c) {
                const float w = caw1[o * 15 + c];
                am = fmaf(s_mx[c], w, am);
                aa = fmaf(s_av[c], w, aa);
            }
            t = fmaf(fmaxf(am, 0.0f) + fmaxf(aa, 0.0f), caw2[tid * 3 + o], t);
        }
        s_ca[tid] = sigmf(t);
    }
    __syncthreads();
    float og[15];
    if (tid < NB) {
        const int n = tid;
        float smx = -INFINITY, ssum = 0.0f;
        #pragma unroll
        for (int c = 0; c < 15; ++c) {
            const int lidx = c / 5, cc = c - lidx * 5;
            const float v = s_xt[lidx][n][cc] * s_ca[c];
            og[c] = v;
            smx = fmaxf(smx, v);
            ssum += v;
        }
        s_smax[n]  = smx;
        s_smean[n] = ssum * (1.0f / 15.0f);
    }
    __syncthreads();
    // 3x1 spatial conv (only kw=1 column of 3x3 survives W=1 padding) + residual
    if (tid < NB) {
        const int n = tid;
        float t = sab[0];
        #pragma unroll
        for (int kh = 0; kh < 3; ++kh) {
            const int nn = n - 1 + kh;
            const int ncl = nn < 0 ? 0 : (nn > NB - 1 ? NB - 1 : nn);
            const float msk = (nn >= 0 && nn < NB) ? 1.0f : 0.0f;
            t += msk * (s_smax[ncl] * saw[kh * 3 + 1] + s_smean[ncl] * saw[9 + kh * 3 + 1]);
        }
        const float sa = sigmf(t);
        #pragma unroll
        for (int c = 0; c < 15; ++c) {
            const int lidx = c / 5, cc = c - lidx * 5;
            s_g[c * NB + n] = og[c] * sa + s_xt[lidx][n][cc];
        }
    }
    __syncthreads();

    // ================= FC head =================
    {
        float acc = fc1b[tid];
        const float* wr = fc1w + (size_t)tid * 930;
        #pragma unroll 4
        for (int i = 0; i < 928; i += 2) {
            const float2 wv = *(const float2*)(wr + i);
            const float2 gv = *(const float2*)(&s_g[i]);
            acc = fmaf(wv.x, gv.x, fmaf(wv.y, gv.y, acc));
        }
        acc += wr[928] * s_g[928] + wr[929] * s_g[929];
        s_h1[tid] = fmaxf(acc, 0.0f);
    }
    __syncthreads();
    {
        float acc = fc2b[tid];
        const float* wr = fc2w + tid * 64;
        #pragma unroll
        for (int k = 0; k < 64; k += 4) {
            const float4 wv = *(const float4*)(wr + k);
            acc = fmaf(wv.x, s_h1[k], acc);
            acc = fmaf(wv.y, s_h1[k + 1], acc);
            acc = fmaf(wv.z, s_h1[k + 2], acc);
            acc = fmaf(wv.w, s_h1[k + 3], acc);
        }
        g_out[(size_t)b * 64 + tid] = fmaxf(acc, 0.0f);
    }
}

extern "C" void kernel_launch(void* const* d_in, const int* in_sizes, int n_in,
                              void* d_out, int out_size, void* d_ws, size_t ws_size,
                              hipStream_t stream) {
    const float* X    = (const float*)d_in[0];
    const float* C0W  = (const float*)d_in[1];
    const float* C0B  = (const float*)d_in[2];
    const float* M0   = (const float*)d_in[3];
    const float* F0W  = (const float*)d_in[4];
    const float* F0B  = (const float*)d_in[5];
    const float* G0W  = (const float*)d_in[6];
    const float* G0B  = (const float*)d_in[7];
    const float* C1W  = (const float*)d_in[8];
    const float* C1B  = (const float*)d_in[9];
    const float* M1   = (const float*)d_in[10];
    const float* F1W  = (const float*)d_in[11];
    const float* F1B  = (const float*)d_in[12];
    const float* G1W  = (const float*)d_in[13];
    const float* G1B  = (const float*)d_in[14];
    const float* CAW1 = (const float*)d_in[15];
    const float* CAW2 = (const float*)d_in[16];
    const float* SAW  = (const float*)d_in[17];
    const float* SAB  = (const float*)d_in[18];
    const float* FC1W = (const float*)d_in[19];
    const float* FC1B = (const float*)d_in[20];
    const float* FC2W = (const float*)d_in[21];
    const float* FC2B = (const float*)d_in[22];

    const int B = in_sizes[0] / (NC * NB);

    encoder_kernel<<<B, 64, 0, stream>>>(
        X, C0W, C0B, M0, F0W, F0B, G0W, G0B,
        C1W, C1B, M1, F1W, F1B, G1W, G1B,
        CAW1, CAW2, SAW, SAB, FC1W, FC1B, FC2W, FC2B,
        (float*)d_out);
}

// Round 3
// 260.947 us; speedup vs baseline: 2.0280x; 1.2788x over previous
//
#include <hip/hip_runtime.h>

#define NB 62
#define NC 5
#define KTOP 49

typedef unsigned short ushort_t;
typedef unsigned int uint_t;

__device__ __forceinline__ float sigmf(float x) {
    return 1.0f / (1.0f + __expf(-x));
}

__device__ __forceinline__ ushort_t f2b(float f) {   // f32 -> bf16 (RNE)
    union { float f; uint_t u; } cv; cv.f = f;
    uint_t r = (cv.u + 0x7fffu + ((cv.u >> 16) & 1u)) >> 16;
    return (ushort_t)r;
}
__device__ __forceinline__ float b2f(ushort_t h) {   // bf16 -> f32 (exact)
    union { uint_t u; float f; } cv; cv.u = ((uint_t)h) << 16;
    return cv.f;
}
__device__ __forceinline__ float blo(uint_t w) {     // low bf16 of dword
    union { uint_t u; float f; } cv; cv.u = w << 16; return cv.f;
}
__device__ __forceinline__ float bhi(uint_t w) {     // high bf16 of dword
    union { uint_t u; float f; } cv; cv.u = w & 0xffff0000u; return cv.f;
}

__device__ __forceinline__ float tmax62(const float* a) {
    float t0 = a[0], t1 = a[1], t2 = a[2], t3 = a[3];
    #pragma unroll
    for (int m = 4; m < 60; m += 4) {
        t0 = fmaxf(t0, a[m]);     t1 = fmaxf(t1, a[m + 1]);
        t2 = fmaxf(t2, a[m + 2]); t3 = fmaxf(t3, a[m + 3]);
    }
    t0 = fmaxf(t0, a[60]); t1 = fmaxf(t1, a[61]);
    return fmaxf(fmaxf(t0, t1), fmaxf(t2, t3));
}
__device__ __forceinline__ float tsum62(const float* a) {
    float t0 = a[0], t1 = a[1], t2 = a[2], t3 = a[3];
    #pragma unroll
    for (int m = 4; m < 60; m += 4) {
        t0 += a[m]; t1 += a[m + 1]; t2 += a[m + 2]; t3 += a[m + 3];
    }
    t0 += a[60]; t1 += a[61];
    return (t0 + t1) + (t2 + t3);
}

// Repack FC weights into d_ws: fc1w[64][930] -> bf16 [117][64][8] (zero-pad to 936),
// fc2w[64][64] -> f32 [16][64][4]. Makes the FC loops fully coalesced.
__global__ void repack_kernel(const float* __restrict__ fc1w,
                              const float* __restrict__ fc2w,
                              ushort_t* __restrict__ w1o,
                              float* __restrict__ w2o) {
    const int i = blockIdx.x * 256 + threadIdx.x;
    if (i < 117 * 64 * 8) {
        const int j = i & 7, o = (i >> 3) & 63, i8 = i >> 9;
        const int src = i8 * 8 + j;
        const float v = (src < 930) ? fc1w[o * 930 + src] : 0.0f;
        w1o[i] = f2b(v);
    } else if (i < 117 * 64 * 8 + 16 * 64 * 4) {
        const int i2 = i - 117 * 64 * 8;
        const int j = i2 & 3, o = (i2 >> 2) & 63, k4 = i2 >> 8;
        w2o[i2] = fc2w[o * 64 + k4 * 4 + j];
    }
}

__launch_bounds__(64, 3)
__global__ void encoder_kernel(
    const float* __restrict__ g_x,
    const float* __restrict__ c0w, const float* __restrict__ c0b,
    const float* __restrict__ m0,  const float* __restrict__ f0w,
    const float* __restrict__ f0b, const float* __restrict__ g0w,
    const float* __restrict__ g0b,
    const float* __restrict__ c1w, const float* __restrict__ c1b,
    const float* __restrict__ m1,  const float* __restrict__ f1w,
    const float* __restrict__ f1b, const float* __restrict__ g1w,
    const float* __restrict__ g1b,
    const float* __restrict__ caw1, const float* __restrict__ caw2,
    const float* __restrict__ saw,  const float* __restrict__ sab,
    const float* __restrict__ fc1w, const float* __restrict__ fc1b,
    const float* __restrict__ fc2w, const float* __restrict__ fc2b,
    const ushort_t* __restrict__ w1b, const float* __restrict__ w2p,
    const int use_ws,
    float* __restrict__ g_out)
{
    const int b   = blockIdx.x;
    const int tid = threadIdx.x;

    // LDS ~15.9 KB -> 10 blocks/CU:
    //   s_adjh bf16 [62][66] = 8184  (row write 2-way free; col read conflict-free)
    //   s_xm   f32  [62][12] = 2976  ([0-3]=xc,[4-7]=mem,[8]=xc4,[9]=mem4; 48B stride, 16B aligned)
    //   s_xt   f32  [3][62][5] = 3720
    //   smalls 960
    __shared__ __align__(16) ushort_t s_adjh[NB * 66];
    __shared__ __align__(16) float s_xm[NB][12];
    __shared__ float s_xt[3][NB][NC];
    __shared__ float s_mx[16], s_av[16], s_ca[16];
    __shared__ float s_smax[64], s_smean[64];
    __shared__ __align__(16) float s_h1[64];

    float* s_g = (float*)s_adjh;  // 936 f32 aliased onto adjacency (disjoint lifetime)

    for (int i = tid; i < NC * NB; i += 64) {
        const int c = i / NB, n = i - c * NB;
        s_xt[0][n][c] = g_x[(size_t)b * (NC * NB) + i];
    }
    __syncthreads();

    const float scale = 0.44721359549995793f; // 1/sqrt(5)

    for (int l = 0; l < 2; ++l) {
        const float* conv_w = l ? c1w : c0w;
        const float* conv_b = l ? c1b : c0b;
        const float* memp   = l ? m1  : m0;
        const float* gfc_w  = l ? f1w : f0w;
        const float* gfc_b  = l ? f1b : f0b;
        const float* gcn_w  = l ? g1w : g0w;
        const float* gcn_b  = l ? g1b : g0b;

        for (int i = tid; i < NC * NB; i += 64) {
            const int c = i / NB, m = i - c * NB;
            s_xm[m][c < 4 ? 4 + c : 9] = memp[i];
        }

        float cw[25], cb[5], gw[25], gb[5];
        #pragma unroll
        for (int i = 0; i < 25; ++i) cw[i] = conv_w[i];
        #pragma unroll
        for (int i = 0; i < 5; ++i)  cb[i] = conv_b[i];
        #pragma unroll
        for (int i = 0; i < 25; ++i) gw[i] = gcn_w[i];
        #pragma unroll
        for (int i = 0; i < 5; ++i)  gb[i] = gcn_b[i];
        const float w0 = gfc_w[0], w1 = gfc_w[1], b0 = gfc_b[0];

        // ---- conv1x1 ----
        float xo0 = 0, xo1 = 0, xo2 = 0, xo3 = 0, xo4 = 0;
        if (tid < NB) {
            const int n = tid;
            float xn[5];
            #pragma unroll
            for (int c = 0; c < 5; ++c) xn[c] = s_xt[l][n][c];
            xo0 = cb[0]; xo1 = cb[1]; xo2 = cb[2]; xo3 = cb[3]; xo4 = cb[4];
            #pragma unroll
            for (int c = 0; c < 5; ++c) {
                xo0 = fmaf(cw[0 * 5 + c], xn[c], xo0);
                xo1 = fmaf(cw[1 * 5 + c], xn[c], xo1);
                xo2 = fmaf(cw[2 * 5 + c], xn[c], xo2);
                xo3 = fmaf(cw[3 * 5 + c], xn[c], xo3);
                xo4 = fmaf(cw[4 * 5 + c], xn[c], xo4);
            }
            s_xm[n][0] = xo0; s_xm[n][1] = xo1; s_xm[n][2] = xo2;
            s_xm[n][3] = xo3; s_xm[n][8] = xo4;
        }
        __syncthreads();

        // ---- row phase: thread n owns row n ----
        if (tid < NB) {
            float r1[NB];
            float r2[64];
            #pragma unroll
            for (int m = 0; m < NB; ++m) {
                const float4 xc03 = *(const float4*)&s_xm[m][0];
                const float4 me03 = *(const float4*)&s_xm[m][4];
                const float2 t45  = *(const float2*)&s_xm[m][8];
                float s1 = xo0 * me03.x + xo1 * me03.y + xo2 * me03.z + xo3 * me03.w + xo4 * t45.y;
                float s2 = xo0 * xc03.x + xo1 * xc03.y + xo2 * xc03.z + xo3 * xc03.w + xo4 * t45.x;
                r1[m] = fmaxf(s1 * scale, 0.0f);
                r2[m] = fmaxf(s2 * scale, 0.0f);
            }
            const float mx1 = tmax62(r1);
            #pragma unroll
            for (int m = 0; m < NB; ++m) r1[m] = __expf(r1[m] - mx1);
            const float inv1 = 1.0f / tsum62(r1);
            const float mx2 = tmax62(r2);
            #pragma unroll
            for (int m = 0; m < NB; ++m) r2[m] = __expf(r2[m] - mx2);
            const float inv2 = 1.0f / tsum62(r2);
            #pragma unroll
            for (int m = 0; m < NB; ++m)
                r1[m] = b0 + (r1[m] * inv1) * w0 + (r2[m] * inv2) * w1;
            const float mxa = tmax62(r1);
            #pragma unroll
            for (int m = 0; m < NB; ++m) r1[m] = __expf(r1[m] - mxa);
            const float inva = 1.0f / tsum62(r1);
            #pragma unroll
            for (int m = 0; m < NB; ++m) r1[m] *= inva;

            // ---- 49th-largest via value-only bitonic sort of a copy ----
            #pragma unroll
            for (int m = 0; m < NB; ++m) r2[m] = r1[m];
            r2[62] = INFINITY; r2[63] = INFINITY;
            #pragma unroll
            for (int k = 2; k <= 64; k <<= 1) {
                #pragma unroll
                for (int j = k >> 1; j > 0; j >>= 1) {
                    #pragma unroll
                    for (int i = 0; i < 64; ++i) {
                        const int p = i ^ j;
                        if (p > i) {
                            const bool up = ((i & k) == 0);
                            const float a = r2[i], c = r2[p];
                            r2[i] = up ? fminf(a, c) : fmaxf(a, c);
                            r2[p] = up ? fmaxf(a, c) : fminf(a, c);
                        }
                    }
                }
            }
            const float vth = r2[13]; // 14th smallest == 49th largest

            // ---- tie-aware selection == jax.lax.top_k (lower index first) ----
            int gc0 = 0, gc1 = 0, gc2 = 0, gc3 = 0;
            #pragma unroll
            for (int m = 0; m < 60; m += 4) {
                gc0 += (r1[m] > vth);     gc1 += (r1[m + 1] > vth);
                gc2 += (r1[m + 2] > vth); gc3 += (r1[m + 3] > vth);
            }
            gc0 += (r1[60] > vth); gc1 += (r1[61] > vth);
            const int G = (gc0 + gc1) + (gc2 + gc3);
            int eq = 0;
            const int n = tid;
            #pragma unroll
            for (int m = 0; m < NB; ++m) {
                const bool e  = (r1[m] == vth);
                const bool ss = (r1[m] > vth) || (e && (G + eq) < KTOP);
                s_adjh[n * 66 + m] = f2b(ss ? r1[m] : 0.0f);
                eq += e ? 1 : 0;
            }
        }
        __syncthreads();

        // ---- diffusion + gcn mix + skip: thread m computes output column m ----
        if (tid < NB) {
            const int m = tid;
            float y0 = 0, y1 = 0, y2 = 0, y3 = 0, y4 = 0;
            for (int n = 0; n < NB; ++n) {
                const float a = b2f(s_adjh[n * 66 + m]);
                const float4 xv = *(const float4*)&s_xm[n][0];
                const float  xv4 = s_xm[n][8];
                y0 = fmaf(xv.x, a, y0); y1 = fmaf(xv.y, a, y1); y2 = fmaf(xv.z, a, y2);
                y3 = fmaf(xv.w, a, y3); y4 = fmaf(xv4, a, y4);
            }
            #pragma unroll
            for (int o = 0; o < 5; ++o) {
                const float z = gb[o] + gw[o * 5 + 0] * y0 + gw[o * 5 + 1] * y1 +
                                gw[o * 5 + 2] * y2 + gw[o * 5 + 3] * y3 + gw[o * 5 + 4] * y4;
                s_xt[l + 1][m][o] = z + s_xt[l][m][o];
            }
        }
        __syncthreads();
    }

    // ================= CBAM =================
    if (tid < 15) {
        const int lidx = tid / 5, cc = tid - lidx * 5;
        float mxv = -INFINITY, sm = 0.0f;
        for (int n = 0; n < NB; ++n) {
            const float v = s_xt[lidx][n][cc];
            mxv = fmaxf(mxv, v);
            sm += v;
        }
        s_mx[tid] = mxv;
        s_av[tid] = sm * (1.0f / 62.0f);
    }
    __syncthreads();
    if (tid < 15) {
        float t = 0.0f;
        #pragma unroll
        for (int o = 0; o < 3; ++o) {
            float am = 0.0f, aa = 0.0f;
            #pragma unroll
            for (int c = 0; c < 15; ++c) {
                const float w = caw1[o * 15 + c];
                am = fmaf(s_mx[c], w, am);
                aa = fmaf(s_av[c], w, aa);
            }
            t = fmaf(fmaxf(am, 0.0f) + fmaxf(aa, 0.0f), caw2[tid * 3 + o], t);
        }
        s_ca[tid] = sigmf(t);
    }
    __syncthreads();
    float og[15];
    if (tid < NB) {
        const int n = tid;
        float smx = -INFINITY, ssum = 0.0f;
        #pragma unroll
        for (int c = 0; c < 15; ++c) {
            const int lidx = c / 5, cc = c - lidx * 5;
            const float v = s_xt[lidx][n][cc] * s_ca[c];
            og[c] = v;
            smx = fmaxf(smx, v);
            ssum += v;
        }
        s_smax[n]  = smx;
        s_smean[n] = ssum * (1.0f / 15.0f);
    }
    __syncthreads();
    // NOTE: s_adjh is dead from here; s_g aliases it.
    if (tid < NB) {
        const int n = tid;
        float t = sab[0];
        #pragma unroll
        for (int kh = 0; kh < 3; ++kh) {
            const int nn = n - 1 + kh;
            const int ncl = nn < 0 ? 0 : (nn > NB - 1 ? NB - 1 : nn);
            const float msk = (nn >= 0 && nn < NB) ? 1.0f : 0.0f;
            t += msk * (s_smax[ncl] * saw[kh * 3 + 1] + s_smean[ncl] * saw[9 + kh * 3 + 1]);
        }
        const float sa = sigmf(t);
        #pragma unroll
        for (int c = 0; c < 15; ++c) {
            const int lidx = c / 5, cc = c - lidx * 5;
            s_g[c * NB + n] = og[c] * sa + s_xt[lidx][n][cc];
        }
    }
    if (tid < 6) s_g[930 + tid] = 0.0f;   // zero pad to 936
    __syncthreads();

    // ================= FC head =================
    if (use_ws) {
        // fc1: bf16 [117][64][8], fully coalesced (1 KB/instr per wave)
        float acc = fc1b[tid];
        const uint4* w1v = (const uint4*)w1b;
        #pragma unroll 4
        for (int i8 = 0; i8 < 117; ++i8) {
            const uint4 wv = w1v[i8 * 64 + tid];
            const float4 ga = *(const float4*)&s_g[i8 * 8];
            const float4 gb2 = *(const float4*)&s_g[i8 * 8 + 4];
            acc = fmaf(blo(wv.x), ga.x,  acc);
            acc = fmaf(bhi(wv.x), ga.y,  acc);
            acc = fmaf(blo(wv.y), ga.z,  acc);
            acc = fmaf(bhi(wv.y), ga.w,  acc);
            acc = fmaf(blo(wv.z), gb2.x, acc);
            acc = fmaf(bhi(wv.z), gb2.y, acc);
            acc = fmaf(blo(wv.w), gb2.z, acc);
            acc = fmaf(bhi(wv.w), gb2.w, acc);
        }
        s_h1[tid] = fmaxf(acc, 0.0f);
        __syncthreads();
        float acc2 = fc2b[tid];
        #pragma unroll
        for (int k4 = 0; k4 < 16; ++k4) {
            const float4 wv = *(const float4*)(w2p + k4 * 256 + tid * 4);
            const float4 hv = *(const float4*)&s_h1[k4 * 4];
            acc2 = fmaf(wv.x, hv.x, acc2);
            acc2 = fmaf(wv.y, hv.y, acc2);
            acc2 = fmaf(wv.z, hv.z, acc2);
            acc2 = fmaf(wv.w, hv.w, acc2);
        }
        g_out[(size_t)b * 64 + tid] = fmaxf(acc2, 0.0f);
    } else {
        // fallback: direct (uncoalesced) weight reads
        float acc = fc1b[tid];
        const float* wr = fc1w + (size_t)tid * 930;
        #pragma unroll 4
        for (int i = 0; i < 928; i += 2) {
            const float2 wv = *(const float2*)(wr + i);
            const float2 gv = *(const float2*)(&s_g[i]);
            acc = fmaf(wv.x, gv.x, fmaf(wv.y, gv.y, acc));
        }
        acc += wr[928] * s_g[928] + wr[929] * s_g[929];
        s_h1[tid] = fmaxf(acc, 0.0f);
        __syncthreads();
        float acc2 = fc2b[tid];
        const float* wr2 = fc2w + tid * 64;
        #pragma unroll
        for (int k = 0; k < 64; k += 4) {
            const float4 wv = *(const float4*)(wr2 + k);
            acc2 = fmaf(wv.x, s_h1[k], acc2);
            acc2 = fmaf(wv.y, s_h1[k + 1], acc2);
            acc2 = fmaf(wv.z, s_h1[k + 2], acc2);
            acc2 = fmaf(wv.w, s_h1[k + 3], acc2);
        }
        g_out[(size_t)b * 64 + tid] = fmaxf(acc2, 0.0f);
    }
}

extern "C" void kernel_launch(void* const* d_in, const int* in_sizes, int n_in,
                              void* d_out, int out_size, void* d_ws, size_t ws_size,
                              hipStream_t stream) {
    const float* X    = (const float*)d_in[0];
    const float* C0W  = (const float*)d_in[1];
    const float* C0B  = (const float*)d_in[2];
    const float* M0   = (const float*)d_in[3];
    const float* F0W  = (const float*)d_in[4];
    const float* F0B  = (const float*)d_in[5];
    const float* G0W  = (const float*)d_in[6];
    const float* G0B  = (const float*)d_in[7];
    const float* C1W  = (const float*)d_in[8];
    const float* C1B  = (const float*)d_in[9];
    const float* M1   = (const float*)d_in[10];
    const float* F1W  = (const float*)d_in[11];
    const float* F1B  = (const float*)d_in[12];
    const float* G1W  = (const float*)d_in[13];
    const float* G1B  = (const float*)d_in[14];
    const float* CAW1 = (const float*)d_in[15];
    const float* CAW2 = (const float*)d_in[16];
    const float* SAW  = (const float*)d_in[17];
    const float* SAB  = (const float*)d_in[18];
    const float* FC1W = (const float*)d_in[19];
    const float* FC1B = (const float*)d_in[20];
    const float* FC2W = (const float*)d_in[21];
    const float* FC2B = (const float*)d_in[22];

    const int B = in_sizes[0] / (NC * NB);

    const size_t W1_BYTES = 117 * 64 * 8 * sizeof(ushort_t); // 119808
    const size_t W2_BYTES = 16 * 64 * 4 * sizeof(float);     // 16384
    const int use_ws = (ws_size >= W1_BYTES + W2_BYTES) ? 1 : 0;
    ushort_t* w1b = (ushort_t*)d_ws;
    float*    w2p = (float*)((char*)d_ws + W1_BYTES);

    if (use_ws) {
        repack_kernel<<<250, 256, 0, stream>>>(FC1W, FC2W, w1b, w2p);
    }

    encoder_kernel<<<B, 64, 0, stream>>>(
        X, C0W, C0B, M0, F0W, F0B, G0W, G0B,
        C1W, C1B, M1, F1W, F1B, G1W, G1B,
        CAW1, CAW2, SAW, SAB, FC1W, FC1B, FC2W, FC2B,
        w1b, w2p, use_ws,
        (float*)d_out);
}

// Round 4
// 250.446 us; speedup vs baseline: 2.1130x; 1.0419x over previous
//
#include <hip/hip_runtime.h>

#define NB 62
#define NC 5
#define KTOP 49

typedef unsigned short ushort_t;
typedef unsigned int uint_t;

__device__ __forceinline__ float sigmf(float x) {
    return 1.0f / (1.0f + __expf(-x));
}

__device__ __forceinline__ ushort_t f2b(float f) {   // f32 -> bf16 (RNE)
    union { float f; uint_t u; } cv; cv.f = f;
    uint_t r = (cv.u + 0x7fffu + ((cv.u >> 16) & 1u)) >> 16;
    return (ushort_t)r;
}
__device__ __forceinline__ float b2f(ushort_t h) {   // bf16 -> f32 (exact)
    union { uint_t u; float f; } cv; cv.u = ((uint_t)h) << 16;
    return cv.f;
}
__device__ __forceinline__ float blo(uint_t w) {     // low bf16 of dword
    union { uint_t u; float f; } cv; cv.u = w << 16; return cv.f;
}
__device__ __forceinline__ float bhi(uint_t w) {     // high bf16 of dword
    union { uint_t u; float f; } cv; cv.u = w & 0xffff0000u; return cv.f;
}

__device__ __forceinline__ float tmax62(const float* a) {
    float t0 = a[0], t1 = a[1], t2 = a[2], t3 = a[3];
    #pragma unroll
    for (int m = 4; m < 60; m += 4) {
        t0 = fmaxf(t0, a[m]);     t1 = fmaxf(t1, a[m + 1]);
        t2 = fmaxf(t2, a[m + 2]); t3 = fmaxf(t3, a[m + 3]);
    }
    t0 = fmaxf(t0, a[60]); t1 = fmaxf(t1, a[61]);
    return fmaxf(fmaxf(t0, t1), fmaxf(t2, t3));
}
__device__ __forceinline__ float tsum62(const float* a) {
    float t0 = a[0], t1 = a[1], t2 = a[2], t3 = a[3];
    #pragma unroll
    for (int m = 4; m < 60; m += 4) {
        t0 += a[m]; t1 += a[m + 1]; t2 += a[m + 2]; t3 += a[m + 3];
    }
    t0 += a[60]; t1 += a[61];
    return (t0 + t1) + (t2 + t3);
}

// Repack FC weights into d_ws: fc1w[64][930] -> bf16 [117][64][8] (zero-pad to 936),
// fc2w[64][64] -> f32 [16][64][4]. Makes the FC loops fully coalesced.
__global__ void repack_kernel(const float* __restrict__ fc1w,
                              const float* __restrict__ fc2w,
                              ushort_t* __restrict__ w1o,
                              float* __restrict__ w2o) {
    const int i = blockIdx.x * 256 + threadIdx.x;
    if (i < 117 * 64 * 8) {
        const int j = i & 7, o = (i >> 3) & 63, i8 = i >> 9;
        const int src = i8 * 8 + j;
        const float v = (src < 930) ? fc1w[o * 930 + src] : 0.0f;
        w1o[i] = f2b(v);
    } else if (i < 117 * 64 * 8 + 16 * 64 * 4) {
        const int i2 = i - 117 * 64 * 8;
        const int j = i2 & 3, o = (i2 >> 2) & 63, k4 = i2 >> 8;
        w2o[i2] = fc2w[o * 64 + k4 * 4 + j];
    }
}

// waves_per_eu(2,3): budget 512/2=256 VGPRs, and the allocator's occupancy
// heuristic may NOT chase >3 waves/EU (round-3 failure mode: min-only bound
// let it target 6 waves/EU -> 84 VGPRs -> ~5 MB scratch traffic per dispatch).
// Peak live set is ~136 (r1[62]+r2[64]+scalars); LDS (15.9 KB) limits
// occupancy to 10 blocks/CU regardless.
__global__ void __launch_bounds__(64) __attribute__((amdgpu_waves_per_eu(2, 3)))
encoder_kernel(
    const float* __restrict__ g_x,
    const float* __restrict__ c0w, const float* __restrict__ c0b,
    const float* __restrict__ m0,  const float* __restrict__ f0w,
    const float* __restrict__ f0b, const float* __restrict__ g0w,
    const float* __restrict__ g0b,
    const float* __restrict__ c1w, const float* __restrict__ c1b,
    const float* __restrict__ m1,  const float* __restrict__ f1w,
    const float* __restrict__ f1b, const float* __restrict__ g1w,
    const float* __restrict__ g1b,
    const float* __restrict__ caw1, const float* __restrict__ caw2,
    const float* __restrict__ saw,  const float* __restrict__ sab,
    const float* __restrict__ fc1w, const float* __restrict__ fc1b,
    const float* __restrict__ fc2w, const float* __restrict__ fc2b,
    const ushort_t* __restrict__ w1b, const float* __restrict__ w2p,
    const int use_ws,
    float* __restrict__ g_out)
{
    const int b   = blockIdx.x;
    const int tid = threadIdx.x;

    __shared__ __align__(16) ushort_t s_adjh[NB * 66];
    __shared__ __align__(16) float s_xm[NB][12];
    __shared__ float s_xt[3][NB][NC];
    __shared__ float s_mx[16], s_av[16], s_ca[16];
    __shared__ float s_smax[64], s_smean[64];
    __shared__ __align__(16) float s_h1[64];

    float* s_g = (float*)s_adjh;  // 936 f32 aliased onto adjacency (disjoint lifetime)

    for (int i = tid; i < NC * NB; i += 64) {
        const int c = i / NB, n = i - c * NB;
        s_xt[0][n][c] = g_x[(size_t)b * (NC * NB) + i];
    }
    __syncthreads();

    const float scale = 0.44721359549995793f; // 1/sqrt(5)

    for (int l = 0; l < 2; ++l) {
        const float* conv_w = l ? c1w : c0w;
        const float* conv_b = l ? c1b : c0b;
        const float* memp   = l ? m1  : m0;
        const float* gfc_w  = l ? f1w : f0w;
        const float* gfc_b  = l ? f1b : f0b;
        const float* gcn_w  = l ? g1w : g0w;
        const float* gcn_b  = l ? g1b : g0b;

        for (int i = tid; i < NC * NB; i += 64) {
            const int c = i / NB, m = i - c * NB;
            s_xm[m][c < 4 ? 4 + c : 9] = memp[i];
        }

        float cw[25], cb[5], gw[25], gb[5];
        #pragma unroll
        for (int i = 0; i < 25; ++i) cw[i] = conv_w[i];
        #pragma unroll
        for (int i = 0; i < 5; ++i)  cb[i] = conv_b[i];
        #pragma unroll
        for (int i = 0; i < 25; ++i) gw[i] = gcn_w[i];
        #pragma unroll
        for (int i = 0; i < 5; ++i)  gb[i] = gcn_b[i];
        const float w0 = gfc_w[0], w1 = gfc_w[1], b0 = gfc_b[0];

        // ---- conv1x1 ----
        float xo0 = 0, xo1 = 0, xo2 = 0, xo3 = 0, xo4 = 0;
        if (tid < NB) {
            const int n = tid;
            float xn[5];
            #pragma unroll
            for (int c = 0; c < 5; ++c) xn[c] = s_xt[l][n][c];
            xo0 = cb[0]; xo1 = cb[1]; xo2 = cb[2]; xo3 = cb[3]; xo4 = cb[4];
            #pragma unroll
            for (int c = 0; c < 5; ++c) {
                xo0 = fmaf(cw[0 * 5 + c], xn[c], xo0);
                xo1 = fmaf(cw[1 * 5 + c], xn[c], xo1);
                xo2 = fmaf(cw[2 * 5 + c], xn[c], xo2);
                xo3 = fmaf(cw[3 * 5 + c], xn[c], xo3);
                xo4 = fmaf(cw[4 * 5 + c], xn[c], xo4);
            }
            s_xm[n][0] = xo0; s_xm[n][1] = xo1; s_xm[n][2] = xo2;
            s_xm[n][3] = xo3; s_xm[n][8] = xo4;
        }
        __syncthreads();

        // ---- row phase: thread n owns row n ----
        if (tid < NB) {
            float r1[NB];
            float r2[64];
            #pragma unroll
            for (int m = 0; m < NB; ++m) {
                const float4 xc03 = *(const float4*)&s_xm[m][0];
                const float4 me03 = *(const float4*)&s_xm[m][4];
                const float2 t45  = *(const float2*)&s_xm[m][8];
                float s1 = xo0 * me03.x + xo1 * me03.y + xo2 * me03.z + xo3 * me03.w + xo4 * t45.y;
                float s2 = xo0 * xc03.x + xo1 * xc03.y + xo2 * xc03.z + xo3 * xc03.w + xo4 * t45.x;
                r1[m] = fmaxf(s1 * scale, 0.0f);
                r2[m] = fmaxf(s2 * scale, 0.0f);
            }
            const float mx1 = tmax62(r1);
            #pragma unroll
            for (int m = 0; m < NB; ++m) r1[m] = __expf(r1[m] - mx1);
            const float inv1 = 1.0f / tsum62(r1);
            const float mx2 = tmax62(r2);
            #pragma unroll
            for (int m = 0; m < NB; ++m) r2[m] = __expf(r2[m] - mx2);
            const float inv2 = 1.0f / tsum62(r2);
            #pragma unroll
            for (int m = 0; m < NB; ++m)
                r1[m] = b0 + (r1[m] * inv1) * w0 + (r2[m] * inv2) * w1;
            const float mxa = tmax62(r1);
            #pragma unroll
            for (int m = 0; m < NB; ++m) r1[m] = __expf(r1[m] - mxa);
            const float inva = 1.0f / tsum62(r1);
            #pragma unroll
            for (int m = 0; m < NB; ++m) r1[m] *= inva;

            // ---- 49th-largest via value-only bitonic sort of a copy ----
            #pragma unroll
            for (int m = 0; m < NB; ++m) r2[m] = r1[m];
            r2[62] = INFINITY; r2[63] = INFINITY;
            #pragma unroll
            for (int k = 2; k <= 64; k <<= 1) {
                #pragma unroll
                for (int j = k >> 1; j > 0; j >>= 1) {
                    #pragma unroll
                    for (int i = 0; i < 64; ++i) {
                        const int p = i ^ j;
                        if (p > i) {
                            const bool up = ((i & k) == 0);
                            const float a = r2[i], c = r2[p];
                            r2[i] = up ? fminf(a, c) : fmaxf(a, c);
                            r2[p] = up ? fmaxf(a, c) : fminf(a, c);
                        }
                    }
                }
            }
            const float vth = r2[13]; // 14th smallest == 49th largest

            // ---- tie-aware selection == jax.lax.top_k (lower index first) ----
            int gc0 = 0, gc1 = 0, gc2 = 0, gc3 = 0;
            #pragma unroll
            for (int m = 0; m < 60; m += 4) {
                gc0 += (r1[m] > vth);     gc1 += (r1[m + 1] > vth);
                gc2 += (r1[m + 2] > vth); gc3 += (r1[m + 3] > vth);
            }
            gc0 += (r1[60] > vth); gc1 += (r1[61] > vth);
            const int G = (gc0 + gc1) + (gc2 + gc3);
            int eq = 0;
            const int n = tid;
            #pragma unroll
            for (int m = 0; m < NB; ++m) {
                const bool e  = (r1[m] == vth);
                const bool ss = (r1[m] > vth) || (e && (G + eq) < KTOP);
                s_adjh[n * 66 + m] = f2b(ss ? r1[m] : 0.0f);
                eq += e ? 1 : 0;
            }
        }
        __syncthreads();

        // ---- diffusion + gcn mix + skip: thread m computes output column m ----
        if (tid < NB) {
            const int m = tid;
            float y0 = 0, y1 = 0, y2 = 0, y3 = 0, y4 = 0;
            for (int n = 0; n < NB; ++n) {
                const float a = b2f(s_adjh[n * 66 + m]);
                const float4 xv = *(const float4*)&s_xm[n][0];
                const float  xv4 = s_xm[n][8];
                y0 = fmaf(xv.x, a, y0); y1 = fmaf(xv.y, a, y1); y2 = fmaf(xv.z, a, y2);
                y3 = fmaf(xv.w, a, y3); y4 = fmaf(xv4, a, y4);
            }
            #pragma unroll
            for (int o = 0; o < 5; ++o) {
                const float z = gb[o] + gw[o * 5 + 0] * y0 + gw[o * 5 + 1] * y1 +
                                gw[o * 5 + 2] * y2 + gw[o * 5 + 3] * y3 + gw[o * 5 + 4] * y4;
                s_xt[l + 1][m][o] = z + s_xt[l][m][o];
            }
        }
        __syncthreads();
    }

    // ================= CBAM =================
    if (tid < 15) {
        const int lidx = tid / 5, cc = tid - lidx * 5;
        float mxv = -INFINITY, sm = 0.0f;
        for (int n = 0; n < NB; ++n) {
            const float v = s_xt[lidx][n][cc];
            mxv = fmaxf(mxv, v);
            sm += v;
        }
        s_mx[tid] = mxv;
        s_av[tid] = sm * (1.0f / 62.0f);
    }
    __syncthreads();
    if (tid < 15) {
        float t = 0.0f;
        #pragma unroll
        for (int o = 0; o < 3; ++o) {
            float am = 0.0f, aa = 0.0f;
            #pragma unroll
            for (int c = 0; c < 15; ++c) {
                const float w = caw1[o * 15 + c];
                am = fmaf(s_mx[c], w, am);
                aa = fmaf(s_av[c], w, aa);
            }
            t = fmaf(fmaxf(am, 0.0f) + fmaxf(aa, 0.0f), caw2[tid * 3 + o], t);
        }
        s_ca[tid] = sigmf(t);
    }
    __syncthreads();
    float og[15];
    if (tid < NB) {
        const int n = tid;
        float smx = -INFINITY, ssum = 0.0f;
        #pragma unroll
        for (int c = 0; c < 15; ++c) {
            const int lidx = c / 5, cc = c - lidx * 5;
            const float v = s_xt[lidx][n][cc] * s_ca[c];
            og[c] = v;
            smx = fmaxf(smx, v);
            ssum += v;
        }
        s_smax[n]  = smx;
        s_smean[n] = ssum * (1.0f / 15.0f);
    }
    __syncthreads();
    // NOTE: s_adjh is dead from here; s_g aliases it.
    if (tid < NB) {
        const int n = tid;
        float t = sab[0];
        #pragma unroll
        for (int kh = 0; kh < 3; ++kh) {
            const int nn = n - 1 + kh;
            const int ncl = nn < 0 ? 0 : (nn > NB - 1 ? NB - 1 : nn);
            const float msk = (nn >= 0 && nn < NB) ? 1.0f : 0.0f;
            t += msk * (s_smax[ncl] * saw[kh * 3 + 1] + s_smean[ncl] * saw[9 + kh * 3 + 1]);
        }
        const float sa = sigmf(t);
        #pragma unroll
        for (int c = 0; c < 15; ++c) {
            const int lidx = c / 5, cc = c - lidx * 5;
            s_g[c * NB + n] = og[c] * sa + s_xt[lidx][n][cc];
        }
    }
    if (tid < 6) s_g[930 + tid] = 0.0f;   // zero pad to 936
    __syncthreads();

    // ================= FC head =================
    if (use_ws) {
        // fc1: bf16 [117][64][8], fully coalesced (1 KB/instr per wave)
        float acc = fc1b[tid];
        const uint4* w1v = (const uint4*)w1b;
        #pragma unroll 4
        for (int i8 = 0; i8 < 117; ++i8) {
            const uint4 wv = w1v[i8 * 64 + tid];
            const float4 ga = *(const float4*)&s_g[i8 * 8];
            const float4 gb2 = *(const float4*)&s_g[i8 * 8 + 4];
            acc = fmaf(blo(wv.x), ga.x,  acc);
            acc = fmaf(bhi(wv.x), ga.y,  acc);
            acc = fmaf(blo(wv.y), ga.z,  acc);
            acc = fmaf(bhi(wv.y), ga.w,  acc);
            acc = fmaf(blo(wv.z), gb2.x, acc);
            acc = fmaf(bhi(wv.z), gb2.y, acc);
            acc = fmaf(blo(wv.w), gb2.z, acc);
            acc = fmaf(bhi(wv.w), gb2.w, acc);
        }
        s_h1[tid] = fmaxf(acc, 0.0f);
        __syncthreads();
        float acc2 = fc2b[tid];
        #pragma unroll
        for (int k4 = 0; k4 < 16; ++k4) {
            const float4 wv = *(const float4*)(w2p + k4 * 256 + tid * 4);
            const float4 hv = *(const float4*)&s_h1[k4 * 4];
            acc2 = fmaf(wv.x, hv.x, acc2);
            acc2 = fmaf(wv.y, hv.y, acc2);
            acc2 = fmaf(wv.z, hv.z, acc2);
            acc2 = fmaf(wv.w, hv.w, acc2);
        }
        g_out[(size_t)b * 64 + tid] = fmaxf(acc2, 0.0f);
    } else {
        // fallback: direct (uncoalesced) weight reads
        float acc = fc1b[tid];
        const float* wr = fc1w + (size_t)tid * 930;
        #pragma unroll 4
        for (int i = 0; i < 928; i += 2) {
            const float2 wv = *(const float2*)(wr + i);
            const float2 gv = *(const float2*)(&s_g[i]);
            acc = fmaf(wv.x, gv.x, fmaf(wv.y, gv.y, acc));
        }
        acc += wr[928] * s_g[928] + wr[929] * s_g[929];
        s_h1[tid] = fmaxf(acc, 0.0f);
        __syncthreads();
        float acc2 = fc2b[tid];
        const float* wr2 = fc2w + tid * 64;
        #pragma unroll
        for (int k = 0; k < 64; k += 4) {
            const float4 wv = *(const float4*)(wr2 + k);
            acc2 = fmaf(wv.x, s_h1[k], acc2);
            acc2 = fmaf(wv.y, s_h1[k + 1], acc2);
            acc2 = fmaf(wv.z, s_h1[k + 2], acc2);
            acc2 = fmaf(wv.w, s_h1[k + 3], acc2);
        }
        g_out[(size_t)b * 64 + tid] = fmaxf(acc2, 0.0f);
    }
}

extern "C" void kernel_launch(void* const* d_in, const int* in_sizes, int n_in,
                              void* d_out, int out_size, void* d_ws, size_t ws_size,
                              hipStream_t stream) {
    const float* X    = (const float*)d_in[0];
    const float* C0W  = (const float*)d_in[1];
    const float* C0B  = (const float*)d_in[2];
    const float* M0   = (const float*)d_in[3];
    const float* F0W  = (const float*)d_in[4];
    const float* F0B  = (const float*)d_in[5];
    const float* G0W  = (const float*)d_in[6];
    const float* G0B  = (const float*)d_in[7];
    const float* C1W  = (const float*)d_in[8];
    const float* C1B  = (const float*)d_in[9];
    const float* M1   = (const float*)d_in[10];
    const float* F1W  = (const float*)d_in[11];
    const float* F1B  = (const float*)d_in[12];
    const float* G1W  = (const float*)d_in[13];
    const float* G1B  = (const float*)d_in[14];
    const float* CAW1 = (const float*)d_in[15];
    const float* CAW2 = (const float*)d_in[16];
    const float* SAW  = (const float*)d_in[17];
    const float* SAB  = (const float*)d_in[18];
    const float* FC1W = (const float*)d_in[19];
    const float* FC1B = (const float*)d_in[20];
    const float* FC2W = (const float*)d_in[21];
    const float* FC2B = (const float*)d_in[22];

    const int B = in_sizes[0] / (NC * NB);

    const size_t W1_BYTES = 117 * 64 * 8 * sizeof(ushort_t); // 119808
    const size_t W2_BYTES = 16 * 64 * 4 * sizeof(float);     // 16384
    const int use_ws = (ws_size >= W1_BYTES + W2_BYTES) ? 1 : 0;
    ushort_t* w1b = (ushort_t*)d_ws;
    float*    w2p = (float*)((char*)d_ws + W1_BYTES);

    if (use_ws) {
        repack_kernel<<<250, 256, 0, stream>>>(FC1W, FC2W, w1b, w2p);
    }

    encoder_kernel<<<B, 64, 0, stream>>>(
        X, C0W, C0B, M0, F0W, F0B, G0W, G0B,
        C1W, C1B, M1, F1W, F1B, G1W, G1B,
        CAW1, CAW2, SAW, SAB, FC1W, FC1B, FC2W, FC2B,
        w1b, w2p, use_ws,
        (float*)d_out);
}